// Round 5
// baseline (1863.306 us; speedup 1.0000x reference)
//
#include <hip/hip_runtime.h>

#define NTOK 262144   // 64*64*64 tokens per batch
#define NCH  64
#define NB   4
#define TOKB 512      // tokens per block (4 waves x 128)

// ws layout (floats): S[4][4] @0, m[4][4][64] @16, rc[4][64] @1040
#define WS_S  0
#define WS_M  16
#define WS_RC 1040

// Fused keys+msum: x read from HBM exactly once, held in registers.
// Lane layout: half = l>>5 picks channel half (0..31 / 32..63); lh = l&31
// picks 4 tokens (lh*4..+3) within the wave's 128-token span. Each lane holds
// xr[32] = float4 x[c0+cc][tok0..3]  (128 VGPRs, all indexing compile-time).
__global__ __launch_bounds__(256)
void ea3d_fused(const float* __restrict__ x, const float* __restrict__ Wk,
                float* __restrict__ ws)
{
    __shared__ __align__(16) float wk4[NCH * 4];   // wk4[c][h]
    __shared__ float ssum[4][4];

    const int tid = threadIdx.x;
    const int w   = tid >> 6;
    const int l   = tid & 63;
    const int b   = blockIdx.y;

    { int c = tid >> 2, h = tid & 3; wk4[(c << 2) + h] = Wk[h * NCH + c]; }
    __syncthreads();

    const int  half = l >> 5;            // channel half
    const int  lh   = l & 31;
    const int  c0   = half << 5;
    const size_t tok0 = (size_t)blockIdx.x * TOKB + (w << 7) + (lh << 2);
    const float* xb = x + ((size_t)b * NCH + c0) * NTOK + tok0;

    // ---- single global read: 32 channel rows, 4 tokens each ----
    float4 xr[32];
    #pragma unroll
    for (int cc = 0; cc < 32; ++cc)
        xr[cc] = *(const float4*)(xb + (size_t)cc * NTOK);

    // ---- keys partial over this half's 32 channels ----
    float k[16];   // k[h*4 + j]
    #pragma unroll
    for (int r = 0; r < 16; ++r) k[r] = 0.f;
    #pragma unroll
    for (int cc = 0; cc < 32; ++cc) {
        float4 wv = *((const float4*)wk4 + (c0 + cc));
        float4 xv = xr[cc];
        k[0]  += wv.x * xv.x; k[1]  += wv.x * xv.y; k[2]  += wv.x * xv.z; k[3]  += wv.x * xv.w;
        k[4]  += wv.y * xv.x; k[5]  += wv.y * xv.y; k[6]  += wv.y * xv.z; k[7]  += wv.y * xv.w;
        k[8]  += wv.z * xv.x; k[9]  += wv.z * xv.y; k[10] += wv.z * xv.z; k[11] += wv.z * xv.w;
        k[12] += wv.w * xv.x; k[13] += wv.w * xv.y; k[14] += wv.w * xv.z; k[15] += wv.w * xv.w;
    }
    // combine channel halves: partner lane = l ^ 32 (same tokens, other half)
    #pragma unroll
    for (int r = 0; r < 16; ++r) k[r] += __shfl_xor(k[r], 32);

    // ---- e = exp(k), S partial ----
    float e[16];
    #pragma unroll
    for (int r = 0; r < 16; ++r) e[r] = __expf(k[r]);
    float sacc[4];
    #pragma unroll
    for (int h = 0; h < 4; ++h)
        sacc[h] = (e[h*4+0] + e[h*4+1]) + (e[h*4+2] + e[h*4+3]);

    // ---- pass 2 (registers only): m[h][c] += e[h][t] * x[c][t] ----
    float* mb = ws + WS_M + (size_t)(b * 4) * NCH;
    #pragma unroll
    for (int cc = 0; cc < 32; ++cc) {
        float4 xv = xr[cc];
        float mc0 = e[0] *xv.x + e[1] *xv.y + e[2] *xv.z + e[3] *xv.w;
        float mc1 = e[4] *xv.x + e[5] *xv.y + e[6] *xv.z + e[7] *xv.w;
        float mc2 = e[8] *xv.x + e[9] *xv.y + e[10]*xv.z + e[11]*xv.w;
        float mc3 = e[12]*xv.x + e[13]*xv.y + e[14]*xv.z + e[15]*xv.w;
        // reduce over the 32 lanes of this half (tokens of the wave)
        #pragma unroll
        for (int off = 16; off; off >>= 1) {
            mc0 += __shfl_xor(mc0, off);
            mc1 += __shfl_xor(mc1, off);
            mc2 += __shfl_xor(mc2, off);
            mc3 += __shfl_xor(mc3, off);
        }
        if (lh == 0) {   // lanes 0 and 32: channels cc and cc+32
            float* mp = mb + (c0 + cc);
            __hip_atomic_fetch_add(mp + 0*NCH, mc0, __ATOMIC_RELAXED, __HIP_MEMORY_SCOPE_AGENT);
            __hip_atomic_fetch_add(mp + 1*NCH, mc1, __ATOMIC_RELAXED, __HIP_MEMORY_SCOPE_AGENT);
            __hip_atomic_fetch_add(mp + 2*NCH, mc2, __ATOMIC_RELAXED, __HIP_MEMORY_SCOPE_AGENT);
            __hip_atomic_fetch_add(mp + 3*NCH, mc3, __ATOMIC_RELAXED, __HIP_MEMORY_SCOPE_AGENT);
        }
    }

    // ---- S: reduce over 64 lanes (halves duplicate -> x0.5), then block+global ----
    #pragma unroll
    for (int h = 0; h < 4; ++h) {
        float v = sacc[h];
        #pragma unroll
        for (int off = 32; off; off >>= 1) v += __shfl_xor(v, off);
        sacc[h] = 0.5f * v;
    }
    if (l == 0) {
        #pragma unroll
        for (int h = 0; h < 4; ++h) ssum[w][h] = sacc[h];
    }
    __syncthreads();
    if (tid < 4) {
        float s = (ssum[0][tid] + ssum[1][tid]) + (ssum[2][tid] + ssum[3][tid]);
        __hip_atomic_fetch_add(ws + WS_S + b * 4 + tid, s,
                               __ATOMIC_RELAXED, __HIP_MEMORY_SCOPE_AGENT);
    }
}

// ---------- finalize: context = Wv*(m/S)+bv ; rc = Wr*context + br ----------
__global__ void ea3d_finalize(const float* __restrict__ Wv, const float* __restrict__ bv,
                              const float* __restrict__ Wr, const float* __restrict__ br,
                              float* __restrict__ ws)
{
    __shared__ float ctx[NB * 32];
    const int tid = threadIdx.x;
    if (tid < 128) {
        int b = tid >> 5, hv = tid & 31, h = hv >> 3;
        float inv = 1.0f / ws[WS_S + b * 4 + h];
        const float* m = ws + WS_M + (b * 4 + h) * NCH;
        const float* wvr = Wv + hv * NCH;
        float acc = 0.f;
        #pragma unroll
        for (int c = 0; c < NCH; ++c) acc += wvr[c] * m[c];
        ctx[b * 32 + hv] = acc * inv + bv[hv];
    }
    __syncthreads();
    int b = tid >> 6, c = tid & 63;
    const float* wrr = Wr + c * 32;
    const float* cb  = ctx + b * 32;
    float acc = br[c];
    #pragma unroll
    for (int hv = 0; hv < 32; ++hv) acc += wrr[hv] * cb[hv];
    ws[WS_RC + b * NCH + c] = acc;
}

// ---------- out = x + rc[b][c] ----------
__global__ __launch_bounds__(256)
void ea3d_add(const float* __restrict__ x, const float* __restrict__ ws,
              float* __restrict__ out)
{
    const int row = blockIdx.y;                 // b*64 + c
    const float rc = ws[WS_RC + row];
    const size_t base = (size_t)row * NTOK;
    const float4* xp = (const float4*)(x + base);
    float4*       op = (float4*)(out + base);
    const int nvec = NTOK / 4;
    for (int i = blockIdx.x * blockDim.x + threadIdx.x; i < nvec;
         i += gridDim.x * blockDim.x) {
        float4 v = xp[i];
        v.x += rc; v.y += rc; v.z += rc; v.w += rc;
        op[i] = v;
    }
}

extern "C" void kernel_launch(void* const* d_in, const int* in_sizes, int n_in,
                              void* d_out, int out_size, void* d_ws, size_t ws_size,
                              hipStream_t stream)
{
    const float* x  = (const float*)d_in[0];
    const float* Wk = (const float*)d_in[1];
    // d_in[2]=bk (cancels in token-softmax); d_in[3]=Wq, d_in[4]=bq (softmax over
    // size-1 head-channel axis -> identically 1.0, so Wq/bq are dead)
    const float* Wv = (const float*)d_in[5];
    const float* bv = (const float*)d_in[6];
    const float* Wr = (const float*)d_in[7];
    const float* br = (const float*)d_in[8];
    float* out = (float*)d_out;
    float* ws  = (float*)d_ws;

    hipMemsetAsync(ws, 0, WS_RC * sizeof(float), stream);   // zero S + m accumulators
    ea3d_fused<<<dim3(NTOK / TOKB, NB), 256, 0, stream>>>(x, Wk, ws);
    ea3d_finalize<<<1, 256, 0, stream>>>(Wv, bv, Wr, br, ws);
    ea3d_add<<<dim3(32, NB * NCH), 256, 0, stream>>>(x, ws, out);
}

// Round 6
// 272.825 us; speedup vs baseline: 6.8297x; 6.8297x over previous
//
#include <hip/hip_runtime.h>

#define NTOK 262144   // 64*64*64 tokens per batch
#define NCH  64
#define NB   4

// ws layout (floats): S[4][4] @0, m[4][4][64] @16, rc[4][64] @1040
#define WS_S  0
#define WS_M  16
#define WS_RC 1040

__device__ __forceinline__ unsigned f2bf_u(float f) {
    unsigned u = __float_as_uint(f);
    u += 0x7fffu + ((u >> 16) & 1u);     // RNE (values are positive normals)
    return u >> 16;
}
__device__ __forceinline__ float bflo(unsigned u) { return __uint_as_float(u << 16); }
__device__ __forceinline__ float bfhi(unsigned u) { return __uint_as_float(u & 0xffff0000u); }

// ---------- P1: keys -> packed bf16 e[b][n][h] + S.  Row-streaming, thread = 4 tokens ----------
__global__ __launch_bounds__(256)
void ea3d_keys(const float* __restrict__ x, const float* __restrict__ Wk,
               unsigned* __restrict__ eu, float* __restrict__ ws)
{
    __shared__ __align__(16) float wk4[NCH * 4];   // wk4[c][h]
    __shared__ float ssum[4][4];

    const int tid = threadIdx.x;
    const int w   = tid >> 6;
    const int b   = blockIdx.y;
    { int c = tid >> 2, h = tid & 3; wk4[(c << 2) + h] = Wk[h * NCH + c]; }
    __syncthreads();

    const int n0 = blockIdx.x * 1024 + tid * 4;
    const float* xb = x + (size_t)b * NCH * NTOK + n0;

    float k[16];                       // k[h*4 + j], j = token 0..3
    #pragma unroll
    for (int r = 0; r < 16; ++r) k[r] = 0.f;

    #pragma unroll 8
    for (int c = 0; c < NCH; ++c) {
        float4 xv = *(const float4*)(xb + (size_t)c * NTOK);   // 1KB/wave contiguous
        float4 wv = *((const float4*)wk4 + c);
        k[0]  += wv.x * xv.x; k[1]  += wv.x * xv.y; k[2]  += wv.x * xv.z; k[3]  += wv.x * xv.w;
        k[4]  += wv.y * xv.x; k[5]  += wv.y * xv.y; k[6]  += wv.y * xv.z; k[7]  += wv.y * xv.w;
        k[8]  += wv.z * xv.x; k[9]  += wv.z * xv.y; k[10] += wv.z * xv.z; k[11] += wv.z * xv.w;
        k[12] += wv.w * xv.x; k[13] += wv.w * xv.y; k[14] += wv.w * xv.z; k[15] += wv.w * xv.w;
    }

    float e[16];
    #pragma unroll
    for (int r = 0; r < 16; ++r) e[r] = __expf(k[r]);

    // pack token-major: token j -> (h0|h1<<16, h2|h3<<16); 32B contiguous/thread
    const size_t tb = (size_t)b * NTOK + n0;     // multiple of 4
    uint4 q0, q1;
    q0.x = f2bf_u(e[0])  | (f2bf_u(e[4])  << 16);
    q0.y = f2bf_u(e[8])  | (f2bf_u(e[12]) << 16);
    q0.z = f2bf_u(e[1])  | (f2bf_u(e[5])  << 16);
    q0.w = f2bf_u(e[9])  | (f2bf_u(e[13]) << 16);
    q1.x = f2bf_u(e[2])  | (f2bf_u(e[6])  << 16);
    q1.y = f2bf_u(e[10]) | (f2bf_u(e[14]) << 16);
    q1.z = f2bf_u(e[3])  | (f2bf_u(e[7])  << 16);
    q1.w = f2bf_u(e[11]) | (f2bf_u(e[15]) << 16);
    ((uint4*)eu)[(tb >> 1) + 0] = q0;
    ((uint4*)eu)[(tb >> 1) + 1] = q1;

    float sacc[4];
    #pragma unroll
    for (int h = 0; h < 4; ++h)
        sacc[h] = (e[h*4+0] + e[h*4+1]) + (e[h*4+2] + e[h*4+3]);
    #pragma unroll
    for (int h = 0; h < 4; ++h) {
        float v = sacc[h];
        #pragma unroll
        for (int off = 32; off; off >>= 1) v += __shfl_xor(v, off);
        sacc[h] = v;
    }
    if ((tid & 63) == 0) {
        #pragma unroll
        for (int h = 0; h < 4; ++h) ssum[w][h] = sacc[h];
    }
    __syncthreads();
    if (tid < 4) {
        float s = (ssum[0][tid] + ssum[1][tid]) + (ssum[2][tid] + ssum[3][tid]);
        __hip_atomic_fetch_add(ws + WS_S + b * 4 + tid, s,
                               __ATOMIC_RELAXED, __HIP_MEMORY_SCOPE_AGENT);
    }
}

// ---------- P2: m[h][c] = sum_n e[h][n]*x[c][n].  8 ch/block, ALL static indexing ----------
__global__ __launch_bounds__(256)
void ea3d_msum(const float* __restrict__ x, const unsigned* __restrict__ eu,
               float* __restrict__ ws)
{
    const int tid = threadIdx.x;
    const int b   = blockIdx.z;
    const int c0  = blockIdx.y << 3;
    const size_t nb0 = (size_t)blockIdx.x * 8192 + tid * 4;
    const float* xb = x + ((size_t)b * NCH + c0) * NTOK;

    float macc[32];                    // macc[cc*4 + h] — static indices only
    #pragma unroll
    for (int r = 0; r < 32; ++r) macc[r] = 0.f;

    for (int s = 0; s < 8; ++s) {
        const size_t n  = nb0 + (size_t)s * 1024;
        const size_t tb = (size_t)b * NTOK + n;
        uint4 q0 = ((const uint4*)eu)[(tb >> 1) + 0];
        uint4 q1 = ((const uint4*)eu)[(tb >> 1) + 1];
        float eh[16];                  // eh[h*4 + j]
        eh[0] = bflo(q0.x); eh[4] = bfhi(q0.x); eh[8]  = bflo(q0.y); eh[12] = bfhi(q0.y);
        eh[1] = bflo(q0.z); eh[5] = bfhi(q0.z); eh[9]  = bflo(q0.w); eh[13] = bfhi(q0.w);
        eh[2] = bflo(q1.x); eh[6] = bfhi(q1.x); eh[10] = bflo(q1.y); eh[14] = bfhi(q1.y);
        eh[3] = bflo(q1.z); eh[7] = bfhi(q1.z); eh[11] = bflo(q1.w); eh[15] = bfhi(q1.w);
        #pragma unroll
        for (int cc = 0; cc < 8; ++cc) {
            float4 xv = *(const float4*)(xb + (size_t)cc * NTOK + n);
            macc[cc*4+0] += eh[0] *xv.x + eh[1] *xv.y + eh[2] *xv.z + eh[3] *xv.w;
            macc[cc*4+1] += eh[4] *xv.x + eh[5] *xv.y + eh[6] *xv.z + eh[7] *xv.w;
            macc[cc*4+2] += eh[8] *xv.x + eh[9] *xv.y + eh[10]*xv.z + eh[11]*xv.w;
            macc[cc*4+3] += eh[12]*xv.x + eh[13]*xv.y + eh[14]*xv.z + eh[15]*xv.w;
        }
    }

    #pragma unroll
    for (int r = 0; r < 32; ++r) {
        float v = macc[r];
        #pragma unroll
        for (int off = 32; off; off >>= 1) v += __shfl_xor(v, off);
        macc[r] = v;
    }
    if ((tid & 63) == 0) {             // one lane per wave: 32 atomics
        float* mb = ws + WS_M + (size_t)(b * 4) * NCH + c0;
        #pragma unroll
        for (int cc = 0; cc < 8; ++cc) {
            #pragma unroll
            for (int h = 0; h < 4; ++h)
                __hip_atomic_fetch_add(mb + h * NCH + cc, macc[cc*4+h],
                                       __ATOMIC_RELAXED, __HIP_MEMORY_SCOPE_AGENT);
        }
    }
}

// ---------- finalize: context = Wv*(m/S)+bv ; rc = Wr*context + br ----------
__global__ void ea3d_finalize(const float* __restrict__ Wv, const float* __restrict__ bv,
                              const float* __restrict__ Wr, const float* __restrict__ br,
                              float* __restrict__ ws)
{
    __shared__ float ctx[NB * 32];
    const int tid = threadIdx.x;
    if (tid < 128) {
        int b = tid >> 5, hv = tid & 31, h = hv >> 3;
        float inv = 1.0f / ws[WS_S + b * 4 + h];
        const float* m = ws + WS_M + (b * 4 + h) * NCH;
        const float* wvr = Wv + hv * NCH;
        float acc = 0.f;
        #pragma unroll
        for (int c = 0; c < NCH; ++c) acc += wvr[c] * m[c];
        ctx[b * 32 + hv] = acc * inv + bv[hv];
    }
    __syncthreads();
    int b = tid >> 6, c = tid & 63;
    const float* wrr = Wr + c * 32;
    const float* cb  = ctx + b * 32;
    float acc = br[c];
    #pragma unroll
    for (int hv = 0; hv < 32; ++hv) acc += wrr[hv] * cb[hv];
    ws[WS_RC + b * NCH + c] = acc;
}

// ---------- P3: out = x + rc[b][c] ----------
__global__ __launch_bounds__(256)
void ea3d_add(const float* __restrict__ x, const float* __restrict__ ws,
              float* __restrict__ out)
{
    const int row = blockIdx.y;                 // b*64 + c
    const float rc = ws[WS_RC + row];
    const size_t base = (size_t)row * NTOK;
    const float4* xp = (const float4*)(x + base);
    float4*       op = (float4*)(out + base);
    const int nvec = NTOK / 4;
    for (int i = blockIdx.x * blockDim.x + threadIdx.x; i < nvec;
         i += gridDim.x * blockDim.x) {
        float4 v = xp[i];
        v.x += rc; v.y += rc; v.z += rc; v.w += rc;
        op[i] = v;
    }
}

extern "C" void kernel_launch(void* const* d_in, const int* in_sizes, int n_in,
                              void* d_out, int out_size, void* d_ws, size_t ws_size,
                              hipStream_t stream)
{
    const float* x  = (const float*)d_in[0];
    const float* Wk = (const float*)d_in[1];
    // d_in[2]=bk (cancels in token-softmax); d_in[3]=Wq, d_in[4]=bq (softmax over
    // size-1 head-channel axis -> identically 1.0, so Wq/bq are dead)
    const float* Wv = (const float*)d_in[5];
    const float* bv = (const float*)d_in[6];
    const float* Wr = (const float*)d_in[7];
    const float* br = (const float*)d_in[8];
    float* out = (float*)d_out;
    float* ws  = (float*)d_ws;

    // packed bf16 e[b][n][h] (8 MB) lives in the head of d_out:
    // written by P1, read by P2, fully overwritten by P3 afterwards.
    unsigned* eu = (unsigned*)d_out;

    hipMemsetAsync(ws, 0, WS_RC * sizeof(float), stream);   // zero S + m accumulators
    ea3d_keys<<<dim3(NTOK / 1024, NB), 256, 0, stream>>>(x, Wk, eu, ws);
    ea3d_msum<<<dim3(NTOK / 8192, 8, NB), 256, 0, stream>>>(x, eu, ws);
    ea3d_finalize<<<1, 256, 0, stream>>>(Wv, bv, Wr, br, ws);
    ea3d_add<<<dim3(32, NB * NCH), 256, 0, stream>>>(x, ws, out);
}